// Round 14
// baseline (3439.558 us; speedup 1.0000x reference)
//
#include <hip/hip_runtime.h>

#define B_ 64
#define S_ 512
#define I_ 1024
#define H_ 1024
#define G_ 4096   // 4*H
#define WPAD 1032 // LDS row stride in ushort
#define UREG 12   // K-chunks of B held in registers (of 32)

typedef __attribute__((ext_vector_type(4))) float f32x4;
typedef __attribute__((ext_vector_type(8))) short bf16x8;

static __device__ __forceinline__ ushort f2b(float f) {
    union { float f; unsigned u; } v; v.f = f;
    unsigned u = v.u;
    unsigned r = (u + 0x7fffu + ((u >> 16) & 1u)) >> 16;
    return (ushort)r;
}
static __device__ __forceinline__ float b2f(ushort b) {
    union { unsigned u; float f; } v; v.u = ((unsigned)b) << 16; return v.f;
}
static __device__ __forceinline__ bf16x8 cvt8(float4 a, float4 b) {
    bf16x8 r;
    r[0] = (short)f2b(a.x); r[1] = (short)f2b(a.y);
    r[2] = (short)f2b(a.z); r[3] = (short)f2b(a.w);
    r[4] = (short)f2b(b.x); r[5] = (short)f2b(b.y);
    r[6] = (short)f2b(b.z); r[7] = (short)f2b(b.w);
    return r;
}

// ---------------------------------------------------------------------------
// x-projection GEMM (bf16 MFMA), conversion fused: reads X, W_ih as f32,
// converts in-register before the LDS store. Double-buffered LDS: ONE
// __syncthreads per K-step. Output xp[s][cb(64)][b(64)][g*16+cc] (bf16).
// ---------------------------------------------------------------------------
__global__ __launch_bounds__(256) void xproj_mfma(
    const float* __restrict__ X, const float* __restrict__ W,
    const float* __restrict__ bih, const float* __restrict__ bhh,
    ushort* __restrict__ xp)
{
    __shared__ ushort As[2][128][40];
    __shared__ ushort Bs[2][128][40];
    const int tid  = threadIdx.x;
    const int lane = tid & 63;
    const int w    = tid >> 6;
    const int wm   = (w >> 1) * 64, wn = (w & 1) * 64;
    const int m0   = blockIdx.y * 128, n0 = blockIdx.x * 128;

    const int srow   = tid >> 2;        // 0..63 (+64 second chunk)
    const int schunk = (tid & 3) * 8;   // f32/bf16 element offset

    const float* Xr0 = X + (size_t)(m0 + srow) * I_ + schunk;
    const float* Xr1 = X + (size_t)(m0 + srow + 64) * I_ + schunk;
    const float* Wr0 = W + (size_t)(n0 + srow) * I_ + schunk;
    const float* Wr1 = W + (size_t)(n0 + srow + 64) * I_ + schunk;

    f32x4 acc[4][4];
#pragma unroll
    for (int mi = 0; mi < 4; ++mi)
#pragma unroll
        for (int ni = 0; ni < 4; ++ni)
#pragma unroll
            for (int r = 0; r < 4; ++r) acc[mi][ni][r] = 0.f;

    // tile 0: load f32 -> convert -> LDS buf 0
    float4 xa0 = *(const float4*)Xr0, xa1 = *(const float4*)(Xr0 + 4);
    float4 xb0 = *(const float4*)Xr1, xb1 = *(const float4*)(Xr1 + 4);
    float4 wa0 = *(const float4*)Wr0, wa1 = *(const float4*)(Wr0 + 4);
    float4 wb0 = *(const float4*)Wr1, wb1 = *(const float4*)(Wr1 + 4);
    *(bf16x8*)&As[0][srow][schunk]      = cvt8(xa0, xa1);
    *(bf16x8*)&As[0][srow + 64][schunk] = cvt8(xb0, xb1);
    *(bf16x8*)&Bs[0][srow][schunk]      = cvt8(wa0, wa1);
    *(bf16x8*)&Bs[0][srow + 64][schunk] = cvt8(wb0, wb1);
    __syncthreads();

    const int arow = lane & 15;
    const int akg  = (lane >> 4) * 8;

    for (int kt = 0; kt < 32; ++kt) {
        const int cur = kt & 1, nxt = cur ^ 1;
        if (kt < 31) {
            int k0 = (kt + 1) * 32;
            xa0 = *(const float4*)(Xr0 + k0); xa1 = *(const float4*)(Xr0 + k0 + 4);
            xb0 = *(const float4*)(Xr1 + k0); xb1 = *(const float4*)(Xr1 + k0 + 4);
            wa0 = *(const float4*)(Wr0 + k0); wa1 = *(const float4*)(Wr0 + k0 + 4);
            wb0 = *(const float4*)(Wr1 + k0); wb1 = *(const float4*)(Wr1 + k0 + 4);
        }
        bf16x8 af[4], bfv[4];
#pragma unroll
        for (int mi = 0; mi < 4; ++mi)
            af[mi] = *(const bf16x8*)&As[cur][wm + mi * 16 + arow][akg];
#pragma unroll
        for (int ni = 0; ni < 4; ++ni)
            bfv[ni] = *(const bf16x8*)&Bs[cur][wn + ni * 16 + arow][akg];
#pragma unroll
        for (int mi = 0; mi < 4; ++mi)
#pragma unroll
            for (int ni = 0; ni < 4; ++ni)
                acc[mi][ni] = __builtin_amdgcn_mfma_f32_16x16x32_bf16(
                    af[mi], bfv[ni], acc[mi][ni], 0, 0, 0);
        if (kt < 31) {
            *(bf16x8*)&As[nxt][srow][schunk]      = cvt8(xa0, xa1);
            *(bf16x8*)&As[nxt][srow + 64][schunk] = cvt8(xb0, xb1);
            *(bf16x8*)&Bs[nxt][srow][schunk]      = cvt8(wa0, wa1);
            *(bf16x8*)&Bs[nxt][srow + 64][schunk] = cvt8(wb0, wb1);
            __syncthreads();
        }
    }

    float bsum[4];
#pragma unroll
    for (int ni = 0; ni < 4; ++ni) {
        int col = n0 + wn + ni * 16 + (lane & 15);
        bsum[ni] = bih[col] + bhh[col];
    }
#pragma unroll
    for (int mi = 0; mi < 4; ++mi)
#pragma unroll
        for (int ni = 0; ni < 4; ++ni) {
            int col = n0 + wn + ni * 16 + (lane & 15);  // 0..4095
            int g = col >> 10, hc = col & 1023;
            int cb = hc >> 4, cc = hc & 15;
#pragma unroll
            for (int r = 0; r < 4; ++r) {
                int row = m0 + wm + mi * 16 + (lane >> 4) * 4 + r;  // = b*S + s
                int bb = row >> 9, ss = row & 511;
                xp[(((size_t)ss * 64 + cb) * 64 + bb) * 64 + g * 16 + cc] =
                    f2b(acc[mi][ni][r] + bsum[ni]);
            }
        }
}

// ---------------------------------------------------------------------------
// Persistent LSTM recurrence: 256 blocks x 1 wave (1 block/CU) -- the exact
// round-8 configuration (best measured: ~5.1 us/step), except W_hh is read
// as f32 and converted in-register during the one-time LDS fill (conv kernel
// removed). Protocol: producer = packed u32 sc1 stores -> vmcnt(0) -> flag;
// consumer = tight-spin 64-lane flag poll -> bulk A-loads. xp prefetched one
// full step ahead; hseq deferred into the A-load shadow; register-B UREG=12.
// ---------------------------------------------------------------------------
__global__ __launch_bounds__(64, 1) void lstm_persist(
    const float* __restrict__ Whh, const ushort* __restrict__ xp,
    ushort* h_all, int* flags, float* __restrict__ hseq,
    float* __restrict__ hlast, float* __restrict__ clast)
{
    __shared__ ushort Ws[64 * WPAD];  // 132096 B -> 1 block/CU

    const int lane = threadIdx.x;     // single wave
    const int bid  = blockIdx.x;
    const int cb   = bid >> 2;        // column block 0..63
    const int q    = bid & 3;         // batch quarter 0..3
    const int c0   = cb * 16;
    const int l15  = lane & 15;
    const int kg   = lane >> 4;
    const int m0   = q * 16;

    // Load W slice (f32 -> bf16): LDS row r = g*16+cc <- Whh row g*1024+c0+cc
#pragma unroll
    for (int i = 0; i < 128; ++i) {
        int id = lane + 64 * i;
        int r  = id >> 7;             // 0..63
        int k8 = (id & 127) * 8;      // 0..1016
        int g = r >> 4, cc = r & 15;
        const float* src = Whh + (size_t)(g * H_ + c0 + cc) * H_ + k8;
        float4 a0 = *(const float4*)src;
        float4 a1 = *(const float4*)(src + 4);
        *(bf16x8*)&Ws[r * WPAD + k8] = cvt8(a0, a1);
    }

    float creg[4] = {0.f, 0.f, 0.f, 0.f};
    __syncthreads();

    // Register-resident B fragments for K-chunks u = 0..UREG-1
    bf16x8 bh[UREG][4];
#pragma unroll
    for (int u = 0; u < UREG; ++u)
#pragma unroll
        for (int g = 0; g < 4; ++g)
            bh[u][g] = *(const bf16x8*)&Ws[(g * 16 + l15) * WPAD + u * 32 + kg * 8];

    // Prologue: xp prefetch for s=0
    ushort xu[4][4];
    {
        const ushort* xps = xp + ((size_t)0 * 64 + cb) * (64 * 64);
#pragma unroll
        for (int r = 0; r < 4; ++r)
#pragma unroll
            for (int g = 0; g < 4; ++g)
                xu[r][g] = xps[(size_t)(m0 + kg * 4 + r) * 64 + g * 16 + l15];
    }

    float hvp[4];  // previous step's h values (deferred hseq)

    for (int s = 0; s < S_; ++s) {
        const ushort* hp = h_all + (size_t)s * (B_ * H_);
        ushort*       hn = h_all + (size_t)(s + 1) * (B_ * H_);

        // Dataflow wait: tight spin on this quarter-chain's 64 producer flags
        if (s > 0) {
            int* fp = flags + ((size_t)s * 4 + q) * 64 + lane;
            unsigned long long rdy;
            do {
                int f = __hip_atomic_load(fp, __ATOMIC_RELAXED,
                                          __HIP_MEMORY_SCOPE_AGENT);
                rdy = __ballot(f != 0);
            } while (rdy != ~0ULL);
            asm volatile("" ::: "memory");  // pin A-loads after flag check
        }

        // A fragments: h rows m0+l15 (this quarter), full K
        const ushort* Ap = hp + (size_t)(m0 + l15) * H_ + kg * 8;
        bf16x8 a[32];
#pragma unroll
        for (int u = 0; u < 32; ++u) a[u] = *(const bf16x8*)(Ap + u * 32);

        // Deferred hseq stores for step s-1 (fill the A-load shadow)
        if (s > 0) {
#pragma unroll
            for (int r = 0; r < 4; ++r) {
                int bb = m0 + kg * 4 + r;
                unsigned fo = __float_as_uint(hvp[r]);
                unsigned fp2 = __shfl_xor(fo, 1);
                if ((l15 & 1) == 0) {
                    unsigned long long fw = (unsigned long long)fo |
                                            ((unsigned long long)fp2 << 32);
                    *(unsigned long long*)
                        (hseq + ((size_t)bb * S_ + (s - 1)) * H_ + c0 + l15) = fw;
                }
            }
        }

        f32x4 ac0, ac1, ac2, ac3;
#pragma unroll
        for (int r = 0; r < 4; ++r) { ac0[r] = 0.f; ac1[r] = 0.f; ac2[r] = 0.f; ac3[r] = 0.f; }

#pragma unroll
        for (int u = 0; u < UREG; ++u) {
            ac0 = __builtin_amdgcn_mfma_f32_16x16x32_bf16(a[u], bh[u][0], ac0, 0, 0, 0);
            ac1 = __builtin_amdgcn_mfma_f32_16x16x32_bf16(a[u], bh[u][1], ac1, 0, 0, 0);
            ac2 = __builtin_amdgcn_mfma_f32_16x16x32_bf16(a[u], bh[u][2], ac2, 0, 0, 0);
            ac3 = __builtin_amdgcn_mfma_f32_16x16x32_bf16(a[u], bh[u][3], ac3, 0, 0, 0);
        }
#pragma unroll
        for (int u = UREG; u < 32; ++u) {
            const ushort* wp = &Ws[l15 * WPAD + u * 32 + kg * 8];
            bf16x8 b0 = *(const bf16x8*)(wp);
            bf16x8 b1 = *(const bf16x8*)(wp + 16 * WPAD);
            bf16x8 b2 = *(const bf16x8*)(wp + 32 * WPAD);
            bf16x8 b3 = *(const bf16x8*)(wp + 48 * WPAD);
            ac0 = __builtin_amdgcn_mfma_f32_16x16x32_bf16(a[u], b0, ac0, 0, 0, 0);
            ac1 = __builtin_amdgcn_mfma_f32_16x16x32_bf16(a[u], b1, ac1, 0, 0, 0);
            ac2 = __builtin_amdgcn_mfma_f32_16x16x32_bf16(a[u], b2, ac2, 0, 0, 0);
            ac3 = __builtin_amdgcn_mfma_f32_16x16x32_bf16(a[u], b3, ac3, 0, 0, 0);
        }

        // lane-local epilogue (consumes xu prefetched last step)
        float cn[4];
#pragma unroll
        for (int r = 0; r < 4; ++r) {
            float gi = ac0[r] + b2f(xu[r][0]);
            float gf = ac1[r] + b2f(xu[r][1]);
            float gg = ac2[r] + b2f(xu[r][2]);
            float go = ac3[r] + b2f(xu[r][3]);
            float ii = 1.f / (1.f + __expf(-gi));
            float ff = 1.f / (1.f + __expf(-gf));
            float gt = 1.f - 2.f / (__expf(2.f * gg) + 1.f);
            float oo = 1.f / (1.f + __expf(-go));
            cn[r] = ff * creg[r] + ii * gt;
            hvp[r] = oo * (1.f - 2.f / (__expf(2.f * cn[r]) + 1.f));
            creg[r] = cn[r];
        }

        // producer tail: u32-packed sc1 h stores -> drain -> flag (r8-exact)
#pragma unroll
        for (int r = 0; r < 4; ++r) {
            int bb = m0 + kg * 4 + r;
            unsigned hb = (unsigned)f2b(hvp[r]);
            unsigned hpp = __shfl_xor(hb, 1);
            if ((l15 & 1) == 0) {
                unsigned hw = hb | (hpp << 16);
                __hip_atomic_store((unsigned*)(hn + (size_t)bb * H_ + c0 + l15), hw,
                                   __ATOMIC_RELAXED, __HIP_MEMORY_SCOPE_AGENT);
            }
        }
        asm volatile("s_waitcnt vmcnt(0)" ::: "memory");
        if (s < S_ - 1 && lane == 0) {
            __hip_atomic_store(flags + ((size_t)(s + 1) * 4 + q) * 64 + cb,
                               1, __ATOMIC_RELAXED, __HIP_MEMORY_SCOPE_AGENT);
        }

        // xp prefetch for next step (HBM latency hidden across the whole step)
        if (s < S_ - 1) {
            const ushort* xps = xp + ((size_t)(s + 1) * 64 + cb) * (64 * 64);
#pragma unroll
            for (int r = 0; r < 4; ++r)
#pragma unroll
                for (int g = 0; g < 4; ++g)
                    xu[r][g] = xps[(size_t)(m0 + kg * 4 + r) * 64 + g * 16 + l15];
        } else {
            // final step: flush hseq[511] + hlast/clast now
#pragma unroll
            for (int r = 0; r < 4; ++r) {
                int bb = m0 + kg * 4 + r;
                unsigned fo = __float_as_uint(hvp[r]);
                unsigned fp2 = __shfl_xor(fo, 1);
                if ((l15 & 1) == 0) {
                    unsigned long long fw = (unsigned long long)fo |
                                            ((unsigned long long)fp2 << 32);
                    *(unsigned long long*)
                        (hseq + ((size_t)bb * S_ + s) * H_ + c0 + l15) = fw;
                }
                hlast[(size_t)bb * H_ + c0 + l15] = hvp[r];
                clast[(size_t)bb * H_ + c0 + l15] = cn[r];
            }
        }
    }
}

extern "C" void kernel_launch(void* const* d_in, const int* in_sizes, int n_in,
                              void* d_out, int out_size, void* d_ws, size_t ws_size,
                              hipStream_t stream) {
    const float* x   = (const float*)d_in[0];
    const float* Wih = (const float*)d_in[1];
    const float* Whh = (const float*)d_in[2];
    const float* bih = (const float*)d_in[3];
    const float* bhh = (const float*)d_in[4];
    float* out = (float*)d_out;

    // workspace layout (ushort elems)
    ushort* xp    = (ushort*)d_ws;            // 134217728 (268 MB) [s][cb][b][64]
    ushort* h_all = xp + 134217728;           // 513 * 65536 ushorts (67 MB)
    int*    flags = (int*)(h_all + 33619968); // 512*4*64 ints = 512 KB

    float* hseq  = out;
    float* hlast = out + (size_t)B_ * S_ * H_;
    float* clast = hlast + (size_t)B_ * H_;

    hipMemsetAsync(h_all, 0, (size_t)B_ * H_ * sizeof(ushort), stream);  // h_0 = 0
    hipMemsetAsync(flags, 0, (size_t)S_ * 4 * 64 * sizeof(int), stream);

    dim3 gg(G_ / 128, (B_ * S_) / 128);
    xproj_mfma<<<gg, 256, 0, stream>>>(x, Wih, bih, bhh, xp);

    lstm_persist<<<256, 64, 0, stream>>>(Whh, xp, h_all, flags,
                                         hseq, hlast, clast);
}

// Round 15
// 3028.134 us; speedup vs baseline: 1.1359x; 1.1359x over previous
//
#include <hip/hip_runtime.h>

#define B_ 64
#define S_ 512
#define I_ 1024
#define H_ 1024
#define G_ 4096   // 4*H
#define WPAD 1032 // LDS row stride in ushort
#define UREG 12   // K-chunks of B held in registers (of 32)

typedef __attribute__((ext_vector_type(4))) float f32x4;
typedef __attribute__((ext_vector_type(8))) short bf16x8;

static __device__ __forceinline__ ushort f2b(float f) {
    union { float f; unsigned u; } v; v.f = f;
    unsigned u = v.u;
    unsigned r = (u + 0x7fffu + ((u >> 16) & 1u)) >> 16;
    return (ushort)r;
}
static __device__ __forceinline__ float b2f(ushort b) {
    union { unsigned u; float f; } v; v.u = ((unsigned)b) << 16; return v.f;
}

// ---------------------------------------------------------------------------
// fp32 -> bf16 conversion for all three inputs, one fused grid-stride kernel
// (X | W_ih | W_hh laid out back-to-back in the conversion index space).
// ---------------------------------------------------------------------------
__global__ __launch_bounds__(256) void conv_all_kernel(
    const float* __restrict__ x, ushort* __restrict__ xb, int nx4,
    const float* __restrict__ wih, ushort* __restrict__ wihb, int nw4,
    const float* __restrict__ whh, ushort* __restrict__ whhb)
{
    int i = blockIdx.x * blockDim.x + threadIdx.x;
    int stride = gridDim.x * blockDim.x;
    int total = nx4 + 2 * nw4;
    for (; i < total; i += stride) {
        const float* src; ushort* dst; int j;
        if (i < nx4) { src = x; dst = xb; j = i; }
        else if (i < nx4 + nw4) { src = wih; dst = wihb; j = i - nx4; }
        else { src = whh; dst = whhb; j = i - nx4 - nw4; }
        float4 v = ((const float4*)src)[j];
        ushort4 o;
        o.x = f2b(v.x); o.y = f2b(v.y); o.z = f2b(v.z); o.w = f2b(v.w);
        ((ushort4*)dst)[j] = o;
    }
}

// ---------------------------------------------------------------------------
// x-projection GEMM (bf16 MFMA): X[M=b*S+s][I] @ W_ih^T + biases.
// Output layout: xp[s][cb(64)][b(64)][g*16+cc].
// ---------------------------------------------------------------------------
__global__ __launch_bounds__(256) void xproj_mfma(
    const ushort* __restrict__ Xb, const ushort* __restrict__ Wb,
    const float* __restrict__ bih, const float* __restrict__ bhh,
    ushort* __restrict__ xp)
{
    __shared__ ushort As[128][40];
    __shared__ ushort Bs[128][40];
    const int tid  = threadIdx.x;
    const int lane = tid & 63;
    const int w    = tid >> 6;
    const int wm   = (w >> 1) * 64, wn = (w & 1) * 64;
    const int m0   = blockIdx.y * 128, n0 = blockIdx.x * 128;

    const int srow   = tid >> 2;
    const int schunk = (tid & 3) * 8;

    const ushort* Xr0 = Xb + (size_t)(m0 + srow) * I_ + schunk;
    const ushort* Xr1 = Xb + (size_t)(m0 + srow + 64) * I_ + schunk;
    const ushort* Wr0 = Wb + (size_t)(n0 + srow) * I_ + schunk;
    const ushort* Wr1 = Wb + (size_t)(n0 + srow + 64) * I_ + schunk;

    f32x4 acc[4][4];
#pragma unroll
    for (int mi = 0; mi < 4; ++mi)
#pragma unroll
        for (int ni = 0; ni < 4; ++ni)
#pragma unroll
            for (int r = 0; r < 4; ++r) acc[mi][ni][r] = 0.f;

    bf16x8 ra0 = *(const bf16x8*)Xr0;
    bf16x8 ra1 = *(const bf16x8*)Xr1;
    bf16x8 rb0 = *(const bf16x8*)Wr0;
    bf16x8 rb1 = *(const bf16x8*)Wr1;

    const int arow = lane & 15;
    const int akg  = (lane >> 4) * 8;

    for (int kt = 0; kt < 32; ++kt) {
        __syncthreads();
        *(bf16x8*)&As[srow][schunk]      = ra0;
        *(bf16x8*)&As[srow + 64][schunk] = ra1;
        *(bf16x8*)&Bs[srow][schunk]      = rb0;
        *(bf16x8*)&Bs[srow + 64][schunk] = rb1;
        __syncthreads();
        if (kt < 31) {
            int k0 = (kt + 1) * 32;
            ra0 = *(const bf16x8*)(Xr0 + k0);
            ra1 = *(const bf16x8*)(Xr1 + k0);
            rb0 = *(const bf16x8*)(Wr0 + k0);
            rb1 = *(const bf16x8*)(Wr1 + k0);
        }
        bf16x8 af[4], bfv[4];
#pragma unroll
        for (int mi = 0; mi < 4; ++mi)
            af[mi] = *(const bf16x8*)&As[wm + mi * 16 + arow][akg];
#pragma unroll
        for (int ni = 0; ni < 4; ++ni)
            bfv[ni] = *(const bf16x8*)&Bs[wn + ni * 16 + arow][akg];
#pragma unroll
        for (int mi = 0; mi < 4; ++mi)
#pragma unroll
            for (int ni = 0; ni < 4; ++ni)
                acc[mi][ni] = __builtin_amdgcn_mfma_f32_16x16x32_bf16(
                    af[mi], bfv[ni], acc[mi][ni], 0, 0, 0);
    }

    float bsum[4];
#pragma unroll
    for (int ni = 0; ni < 4; ++ni) {
        int col = n0 + wn + ni * 16 + (lane & 15);
        bsum[ni] = bih[col] + bhh[col];
    }
#pragma unroll
    for (int mi = 0; mi < 4; ++mi)
#pragma unroll
        for (int ni = 0; ni < 4; ++ni) {
            int col = n0 + wn + ni * 16 + (lane & 15);  // 0..4095
            int g = col >> 10, hc = col & 1023;
            int cb = hc >> 4, cc = hc & 15;
#pragma unroll
            for (int r = 0; r < 4; ++r) {
                int row = m0 + wm + mi * 16 + (lane >> 4) * 4 + r;  // = b*S + s
                int bb = row >> 9, ss = row & 511;
                xp[(((size_t)ss * 64 + cb) * 64 + bb) * 64 + g * 16 + cc] =
                    f2b(acc[mi][ni][r] + bsum[ni]);
            }
        }
}

// ---------------------------------------------------------------------------
// Persistent LSTM recurrence: 256 blocks x 1 wave (1 block/CU, grid = #CUs).
// The round-8 configuration exactly (best measured: ~5.1 us/step).
// Block (cb, q) = h-cols 16cb..16cb+15 (x4 gates) for batch rows 16q..16q+15.
// 4 independent batch-quarter chains, each on 64 dedicated CUs. Wave<->wave
// dataflow flags (tight spin), xp prefetched a full step ahead, hseq deferred
// into the A-load shadow, producer tail = packed sc1 stores -> vmcnt(0) ->
// flag. Register-B UREG=12.
// ---------------------------------------------------------------------------
__global__ __launch_bounds__(64, 1) void lstm_persist(
    const ushort* __restrict__ Whhb, const ushort* __restrict__ xp,
    ushort* h_all, int* flags, float* __restrict__ hseq,
    float* __restrict__ hlast, float* __restrict__ clast)
{
    __shared__ ushort Ws[64 * WPAD];  // 132096 B -> 1 block/CU

    const int lane = threadIdx.x;     // single wave
    const int bid  = blockIdx.x;
    const int cb   = bid >> 2;        // column block 0..63
    const int q    = bid & 3;         // batch quarter 0..3
    const int c0   = cb * 16;
    const int l15  = lane & 15;
    const int kg   = lane >> 4;
    const int m0   = q * 16;

    // Load W slice: LDS row r = g*16+cc  <-  Whh row g*1024 + c0 + cc
#pragma unroll
    for (int i = 0; i < 128; ++i) {
        int id = lane + 64 * i;
        int r  = id >> 7;
        int k8 = (id & 127) * 8;
        int g = r >> 4, cc = r & 15;
        *(bf16x8*)&Ws[r * WPAD + k8] =
            *(const bf16x8*)(Whhb + (size_t)(g * H_ + c0 + cc) * H_ + k8);
    }

    float creg[4] = {0.f, 0.f, 0.f, 0.f};
    __syncthreads();

    // Register-resident B fragments for K-chunks u = 0..UREG-1
    bf16x8 bh[UREG][4];
#pragma unroll
    for (int u = 0; u < UREG; ++u)
#pragma unroll
        for (int g = 0; g < 4; ++g)
            bh[u][g] = *(const bf16x8*)&Ws[(g * 16 + l15) * WPAD + u * 32 + kg * 8];

    // Prologue: xp prefetch for s=0
    ushort xu[4][4];
    {
        const ushort* xps = xp + ((size_t)0 * 64 + cb) * (64 * 64);
#pragma unroll
        for (int r = 0; r < 4; ++r)
#pragma unroll
            for (int g = 0; g < 4; ++g)
                xu[r][g] = xps[(size_t)(m0 + kg * 4 + r) * 64 + g * 16 + l15];
    }

    float hvp[4];  // previous step's h values (deferred hseq)

    for (int s = 0; s < S_; ++s) {
        const ushort* hp = h_all + (size_t)s * (B_ * H_);
        ushort*       hn = h_all + (size_t)(s + 1) * (B_ * H_);

        // Dataflow wait: tight spin on this quarter-chain's 64 producer flags
        if (s > 0) {
            int* fp = flags + ((size_t)s * 4 + q) * 64 + lane;
            unsigned long long rdy;
            do {
                int f = __hip_atomic_load(fp, __ATOMIC_RELAXED,
                                          __HIP_MEMORY_SCOPE_AGENT);
                rdy = __ballot(f != 0);
            } while (rdy != ~0ULL);
            asm volatile("" ::: "memory");  // pin A-loads after flag check
        }

        // A fragments: h rows m0+l15 (this quarter), full K
        const ushort* Ap = hp + (size_t)(m0 + l15) * H_ + kg * 8;
        bf16x8 a[32];
#pragma unroll
        for (int u = 0; u < 32; ++u) a[u] = *(const bf16x8*)(Ap + u * 32);

        // Deferred hseq stores for step s-1 (fill the A-load shadow)
        if (s > 0) {
#pragma unroll
            for (int r = 0; r < 4; ++r) {
                int bb = m0 + kg * 4 + r;
                unsigned fo = __float_as_uint(hvp[r]);
                unsigned fp2 = __shfl_xor(fo, 1);
                if ((l15 & 1) == 0) {
                    unsigned long long fw = (unsigned long long)fo |
                                            ((unsigned long long)fp2 << 32);
                    *(unsigned long long*)
                        (hseq + ((size_t)bb * S_ + (s - 1)) * H_ + c0 + l15) = fw;
                }
            }
        }

        f32x4 ac0, ac1, ac2, ac3;
#pragma unroll
        for (int r = 0; r < 4; ++r) { ac0[r] = 0.f; ac1[r] = 0.f; ac2[r] = 0.f; ac3[r] = 0.f; }

#pragma unroll
        for (int u = 0; u < UREG; ++u) {
            ac0 = __builtin_amdgcn_mfma_f32_16x16x32_bf16(a[u], bh[u][0], ac0, 0, 0, 0);
            ac1 = __builtin_amdgcn_mfma_f32_16x16x32_bf16(a[u], bh[u][1], ac1, 0, 0, 0);
            ac2 = __builtin_amdgcn_mfma_f32_16x16x32_bf16(a[u], bh[u][2], ac2, 0, 0, 0);
            ac3 = __builtin_amdgcn_mfma_f32_16x16x32_bf16(a[u], bh[u][3], ac3, 0, 0, 0);
        }
#pragma unroll
        for (int u = UREG; u < 32; ++u) {
            const ushort* wp = &Ws[l15 * WPAD + u * 32 + kg * 8];
            bf16x8 b0 = *(const bf16x8*)(wp);
            bf16x8 b1 = *(const bf16x8*)(wp + 16 * WPAD);
            bf16x8 b2 = *(const bf16x8*)(wp + 32 * WPAD);
            bf16x8 b3 = *(const bf16x8*)(wp + 48 * WPAD);
            ac0 = __builtin_amdgcn_mfma_f32_16x16x32_bf16(a[u], b0, ac0, 0, 0, 0);
            ac1 = __builtin_amdgcn_mfma_f32_16x16x32_bf16(a[u], b1, ac1, 0, 0, 0);
            ac2 = __builtin_amdgcn_mfma_f32_16x16x32_bf16(a[u], b2, ac2, 0, 0, 0);
            ac3 = __builtin_amdgcn_mfma_f32_16x16x32_bf16(a[u], b3, ac3, 0, 0, 0);
        }

        // lane-local epilogue (consumes xu prefetched last step)
        float cn[4];
#pragma unroll
        for (int r = 0; r < 4; ++r) {
            float gi = ac0[r] + b2f(xu[r][0]);
            float gf = ac1[r] + b2f(xu[r][1]);
            float gg = ac2[r] + b2f(xu[r][2]);
            float go = ac3[r] + b2f(xu[r][3]);
            float ii = 1.f / (1.f + __expf(-gi));
            float ff = 1.f / (1.f + __expf(-gf));
            float gt = 1.f - 2.f / (__expf(2.f * gg) + 1.f);
            float oo = 1.f / (1.f + __expf(-go));
            cn[r] = ff * creg[r] + ii * gt;
            hvp[r] = oo * (1.f - 2.f / (__expf(2.f * cn[r]) + 1.f));
            creg[r] = cn[r];
        }

        // producer tail: h stores (sc1, packed u32 pairs) -> drain -> flag
#pragma unroll
        for (int r = 0; r < 4; ++r) {
            int bb = m0 + kg * 4 + r;
            unsigned hb = (unsigned)f2b(hvp[r]);
            unsigned hpp = __shfl_xor(hb, 1);
            if ((l15 & 1) == 0) {
                unsigned hw = hb | (hpp << 16);
                __hip_atomic_store((unsigned*)(hn + (size_t)bb * H_ + c0 + l15), hw,
                                   __ATOMIC_RELAXED, __HIP_MEMORY_SCOPE_AGENT);
            }
        }
        asm volatile("s_waitcnt vmcnt(0)" ::: "memory");
        if (s < S_ - 1 && lane == 0) {
            __hip_atomic_store(flags + ((size_t)(s + 1) * 4 + q) * 64 + cb,
                               1, __ATOMIC_RELAXED, __HIP_MEMORY_SCOPE_AGENT);
        }

        // xp prefetch for next step (HBM latency hidden across the whole step)
        if (s < S_ - 1) {
            const ushort* xps = xp + ((size_t)(s + 1) * 64 + cb) * (64 * 64);
#pragma unroll
            for (int r = 0; r < 4; ++r)
#pragma unroll
                for (int g = 0; g < 4; ++g)
                    xu[r][g] = xps[(size_t)(m0 + kg * 4 + r) * 64 + g * 16 + l15];
        } else {
            // final step: flush hseq[511] + hlast/clast now
#pragma unroll
            for (int r = 0; r < 4; ++r) {
                int bb = m0 + kg * 4 + r;
                unsigned fo = __float_as_uint(hvp[r]);
                unsigned fp2 = __shfl_xor(fo, 1);
                if ((l15 & 1) == 0) {
                    unsigned long long fw = (unsigned long long)fo |
                                            ((unsigned long long)fp2 << 32);
                    *(unsigned long long*)
                        (hseq + ((size_t)bb * S_ + s) * H_ + c0 + l15) = fw;
                }
                hlast[(size_t)bb * H_ + c0 + l15] = hvp[r];
                clast[(size_t)bb * H_ + c0 + l15] = cn[r];
            }
        }
    }
}

extern "C" void kernel_launch(void* const* d_in, const int* in_sizes, int n_in,
                              void* d_out, int out_size, void* d_ws, size_t ws_size,
                              hipStream_t stream) {
    const float* x   = (const float*)d_in[0];
    const float* Wih = (const float*)d_in[1];
    const float* Whh = (const float*)d_in[2];
    const float* bih = (const float*)d_in[3];
    const float* bhh = (const float*)d_in[4];
    float* out = (float*)d_out;

    // workspace layout (ushort elems)
    ushort* xp    = (ushort*)d_ws;            // 134217728 (268 MB) [s][cb][b][64]
    ushort* xbf   = xp + 134217728;           // 33554432
    ushort* wihb  = xbf + 33554432;           // 4194304
    ushort* whhb  = wihb + 4194304;           // 4194304
    ushort* h_all = whhb + 4194304;           // 513 * 65536 ushorts (67 MB)
    int*    flags = (int*)(h_all + 33619968); // 512*4*64 ints = 512 KB

    float* hseq  = out;
    float* hlast = out + (size_t)B_ * S_ * H_;
    float* clast = hlast + (size_t)B_ * H_;

    hipMemsetAsync(h_all, 0, (size_t)B_ * H_ * sizeof(ushort), stream);  // h_0 = 0
    hipMemsetAsync(flags, 0, (size_t)S_ * 4 * 64 * sizeof(int), stream);

    conv_all_kernel<<<2048, 256, 0, stream>>>(
        x, xbf, (B_ * S_ * I_) / 4,
        Wih, wihb, (G_ * I_) / 4,
        Whh, whhb);

    dim3 gg(G_ / 128, (B_ * S_) / 128);
    xproj_mfma<<<gg, 256, 0, stream>>>(xbf, wihb, bih, bhh, xp);

    lstm_persist<<<256, 64, 0, stream>>>(whhb, xp, h_all, flags,
                                         hseq, hlast, clast);
}